// Round 2
// baseline (109.874 us; speedup 1.0000x reference)
//
#include <hip/hip_runtime.h>
#include <math.h>

#define TT 10
#define CHN 16
#define HH 16
#define WW 264
#define HW (HH*WW)        // 4224
#define DD (CHN*HW)       // 67584
#define NBLK ((HW+255)/256)  // 17 pixel-blocks
#define NACC 55           // upper-triangular 10x10 pairs

// Compute per-(y,x) bilinear gather plan for all 10 slots of batch b.
// off[s][j] are absolute offsets into ff for channel 0 (add ch*HW per channel);
// wgt[s][j] the bilinear weights (0 for OOB corners / invalid slots).
__device__ __forceinline__ void slot_setup(int b, int p, bool act,
                                           const float4* __restrict__ pose,
                                           int off[TT][4], float wgt[TT][4]) {
    int y = p / WW, x = p - y*WW;
    #pragma unroll
    for (int s = 0; s < TT; ++s) {
        #pragma unroll
        for (int j = 0; j < 4; ++j) { off[s][j] = 0; wgt[s][j] = 0.f; }
        if (!act) continue;
        if (s == TT-1) { off[s][0] = b*DD + p; wgt[s][0] = 1.f; continue; }
        int ts = (TT-1) - s;
        if (ts > b) continue;                       // invalid slot -> zeros
        float4 m = pose[ts-1];                      // {dx, dy, cos, sin}
        float xs = (2.f*(float)x + 1.f)/(float)WW - 1.f;
        float ys = (2.f*(float)y + 1.f)/(float)HH - 1.f;
        float gx =  m.z*xs + m.w*ys + m.x;
        float gy = -m.w*xs + m.z*ys + m.y;
        float ix = ((gx + 1.f)*(float)WW - 1.f)*0.5f;
        float iy = ((gy + 1.f)*(float)HH - 1.f)*0.5f;
        float ix0f = floorf(ix), iy0f = floorf(iy);
        float wx1 = ix - ix0f, wx0 = 1.f - wx1;
        float wy1 = iy - iy0f, wy0 = 1.f - wy1;
        int ix0 = (int)ix0f, iy0 = (int)iy0f;
        int ix1 = ix0 + 1,   iy1 = iy0 + 1;
        bool inx0 = (ix0 >= 0) && (ix0 < WW);
        bool inx1 = (ix1 >= 0) && (ix1 < WW);
        bool iny0 = (iy0 >= 0) && (iy0 < HH);
        bool iny1 = (iy1 >= 0) && (iy1 < HH);
        int xi0 = min(max(ix0, 0), WW-1), xi1 = min(max(ix1, 0), WW-1);
        int yi0 = min(max(iy0, 0), HH-1), yi1 = min(max(iy1, 0), HH-1);
        int base = ts*DD;
        off[s][0] = base + yi0*WW + xi0; wgt[s][0] = (inx0 && iny0) ? wx0*wy0 : 0.f;
        off[s][1] = base + yi0*WW + xi1; wgt[s][1] = (inx1 && iny0) ? wx1*wy0 : 0.f;
        off[s][2] = base + yi1*WW + xi0; wgt[s][2] = (inx0 && iny1) ? wx0*wy1 : 0.f;
        off[s][3] = base + yi1*WW + xi1; wgt[s][3] = (inx1 && iny1) ? wx1*wy1 : 0.f;
    }
}

// Poses for batch b, computed by threads 0..8 (ts=tid+1): pose = P[ts-1] - P[b],
// P = fp32 sequential cumsum of dp (matches reference rounding).
__device__ __forceinline__ void pose_setup(const float* __restrict__ dp, int b,
                                           float4* __restrict__ pose) {
    if (threadIdx.x < TT-1) {
        int ts = (int)threadIdx.x + 1;
        float ax = 0.f, ay = 0.f, az = 0.f;
        for (int j = 0; j < ts-1; ++j) { ax += dp[3*j]; ay += dp[3*j+1]; az += dp[3*j+2]; }
        float bx = 0.f, by = 0.f, bz = 0.f;
        for (int j = 0; j < b; ++j)    { bx += dp[3*j]; by += dp[3*j+1]; bz += dp[3*j+2]; }
        float yaw = az - bz;
        pose[threadIdx.x] = make_float4(ax - bx, ay - by,
                                        (float)cos((double)yaw), (float)sin((double)yaw));
    }
}

// ---------------- kernel A: fused warp + Gram partials -----------------------
__global__ __launch_bounds__(256) void gram_fused_kernel(const float* __restrict__ ff,
                                                         const float* __restrict__ dp,
                                                         float* __restrict__ partial) {
    int b = blockIdx.y;
    int p = blockIdx.x*256 + threadIdx.x;
    __shared__ float4 pose[TT-1];
    pose_setup(dp, b, pose);
    __syncthreads();

    bool act = p < HW;
    int off[TT][4]; float wgt[TT][4];
    slot_setup(b, p, act, pose, off, wgt);

    float acc[NACC];
    #pragma unroll
    for (int k = 0; k < NACC; ++k) acc[k] = 0.f;

    for (int ch = 0; ch < CHN; ++ch) {
        const float* fc = ff + ch*HW;
        float v[TT];
        #pragma unroll
        for (int s = 0; s < TT; ++s)
            v[s] = fc[off[s][0]]*wgt[s][0] + fc[off[s][1]]*wgt[s][1]
                 + fc[off[s][2]]*wgt[s][2] + fc[off[s][3]]*wgt[s][3];
        int k = 0;
        #pragma unroll
        for (int t = 0; t < TT; ++t)
            #pragma unroll
            for (int s2 = t; s2 < TT; ++s2)
                acc[k++] += v[t]*v[s2];
    }

    __shared__ float red[NACC*4];
    int lane = threadIdx.x & 63, wv = threadIdx.x >> 6;
    #pragma unroll
    for (int k = 0; k < NACC; ++k) {
        float a = acc[k];
        #pragma unroll
        for (int o = 32; o > 0; o >>= 1) a += __shfl_down(a, o);
        if (lane == 0) red[k*4 + wv] = a;
    }
    __syncthreads();
    if (threadIdx.x < NACC) {
        float a = red[threadIdx.x*4] + red[threadIdx.x*4+1]
                + red[threadIdx.x*4+2] + red[threadIdx.x*4+3];
        partial[((size_t)b*NBLK + blockIdx.x)*NACC + threadIdx.x] = a;
    }
}

// ---------------- kernel B: softmax weights ----------------------------------
// w[b,s] = (1/T) * sum_t softmax(scores[b,t,:])[s]
__global__ void weights_kernel(const float* __restrict__ partial, float* __restrict__ w) {
    __shared__ float ws[TT*TT];
    int tid = threadIdx.x;
    if (tid < TT*TT) ws[tid] = 0.f;
    __syncthreads();
    if (tid < TT*TT) {
        int b = tid / TT, t = tid % TT;
        float sc[TT];
        for (int s = 0; s < TT; ++s) {
            int a0 = min(t, s), a1 = max(t, s);
            int k = a0*TT - a0*(a0 - 1)/2 + (a1 - a0);  // upper-tri index
            float sum = 0.f;
            for (int c = 0; c < NBLK; ++c)
                sum += partial[((size_t)b*NBLK + c)*NACC + k];
            sc[s] = sum;
        }
        float mx = sc[0];
        for (int s = 1; s < TT; ++s) mx = fmaxf(mx, sc[s]);
        float e[TT]; float den = 0.f;
        for (int s = 0; s < TT; ++s) { e[s] = expf(sc[s] - mx); den += e[s]; }
        float inv = 1.f / den;
        for (int s = 0; s < TT; ++s) atomicAdd(&ws[b*TT + s], e[s]*inv*0.1f);
    }
    __syncthreads();
    if (tid < TT*TT) w[tid] = ws[tid];
}

// ---------------- kernel C: fused warp + weighted output ---------------------
// out[b,:,p] = sum_s w[b,s] * warp_s(ff)[:,p]  (w folded into bilinear weights)
__global__ __launch_bounds__(256) void out_fused_kernel(const float* __restrict__ ff,
                                                        const float* __restrict__ dp,
                                                        const float* __restrict__ w,
                                                        float* __restrict__ out) {
    int b = blockIdx.y;
    int p = blockIdx.x*256 + threadIdx.x;
    __shared__ float4 pose[TT-1];
    __shared__ float wl[TT];
    pose_setup(dp, b, pose);
    if (threadIdx.x < TT) wl[threadIdx.x] = w[b*TT + threadIdx.x];
    __syncthreads();

    bool act = p < HW;
    int off[TT][4]; float wgt[TT][4];
    slot_setup(b, p, act, pose, off, wgt);
    #pragma unroll
    for (int s = 0; s < TT; ++s) {
        float wb = wl[s];
        #pragma unroll
        for (int j = 0; j < 4; ++j) wgt[s][j] *= wb;
    }

    if (!act) return;
    for (int ch = 0; ch < CHN; ++ch) {
        const float* fc = ff + ch*HW;
        float o = 0.f;
        #pragma unroll
        for (int s = 0; s < TT; ++s)
            o += fc[off[s][0]]*wgt[s][0] + fc[off[s][1]]*wgt[s][1]
               + fc[off[s][2]]*wgt[s][2] + fc[off[s][3]]*wgt[s][3];
        out[(size_t)b*DD + ch*HW + p] = o;
    }
}

extern "C" void kernel_launch(void* const* d_in, const int* in_sizes, int n_in,
                              void* d_out, int out_size, void* d_ws, size_t ws_size,
                              hipStream_t stream) {
    const float* ff = (const float*)d_in[0];   // (T, L, C) = (T, D) flat
    const float* dp = (const float*)d_in[1];   // (T, 3)
    float* out = (float*)d_out;                // (T, L, C) flat

    char* ws = (char*)d_ws;
    float* partial = (float*)ws;               // 10*17*55*4 = 37.4 KB
    float* w       = (float*)(ws + 65536);     // 100 floats

    gram_fused_kernel<<<dim3(NBLK, TT), 256, 0, stream>>>(ff, dp, partial);
    weights_kernel   <<<1, 128, 0, stream>>>(partial, w);
    out_fused_kernel <<<dim3(NBLK, TT), 256, 0, stream>>>(ff, dp, w, out);
}

// Round 3
// 101.705 us; speedup vs baseline: 1.0803x; 1.0803x over previous
//
#include <hip/hip_runtime.h>
#include <math.h>

#define TT 10
#define CHN 16
#define HH 16
#define WW 264
#define HW (HH*WW)          // 4224
#define DD (CHN*HW)         // 67584
#define NCH 66              // pixel chunks of 64: HW/64
#define NACC 55             // upper-triangular 10x10 pairs

// Per-(y,x) bilinear gather plan for all 10 slots of batch b.
// off[s][j]: offsets into ff for channel 0 (add ch*HW); wgt[s][j]: weights
// (0 for OOB corners / invalid slots).  Channel-independent.
__device__ __forceinline__ void slot_setup(int b, int p,
                                           const float4* __restrict__ pose,
                                           int off[TT][4], float wgt[TT][4]) {
    int y = p / WW, x = p - y*WW;
    float xs = (2.f*(float)x + 1.f)/(float)WW - 1.f;
    float ys = (2.f*(float)y + 1.f)/(float)HH - 1.f;
    #pragma unroll
    for (int s = 0; s < TT; ++s) {
        #pragma unroll
        for (int j = 0; j < 4; ++j) { off[s][j] = 0; wgt[s][j] = 0.f; }
        if (s == TT-1) { off[s][0] = b*DD + p; wgt[s][0] = 1.f; continue; }
        int ts = (TT-1) - s;
        if (ts > b) continue;                       // invalid slot -> zeros
        float4 m = pose[ts-1];                      // {dx, dy, cos, sin}
        float gx =  m.z*xs + m.w*ys + m.x;
        float gy = -m.w*xs + m.z*ys + m.y;
        float ix = ((gx + 1.f)*(float)WW - 1.f)*0.5f;
        float iy = ((gy + 1.f)*(float)HH - 1.f)*0.5f;
        float ix0f = floorf(ix), iy0f = floorf(iy);
        float wx1 = ix - ix0f, wx0 = 1.f - wx1;
        float wy1 = iy - iy0f, wy0 = 1.f - wy1;
        int ix0 = (int)ix0f, iy0 = (int)iy0f;
        int ix1 = ix0 + 1,   iy1 = iy0 + 1;
        bool inx0 = (ix0 >= 0) && (ix0 < WW);
        bool inx1 = (ix1 >= 0) && (ix1 < WW);
        bool iny0 = (iy0 >= 0) && (iy0 < HH);
        bool iny1 = (iy1 >= 0) && (iy1 < HH);
        int xi0 = min(max(ix0, 0), WW-1), xi1 = min(max(ix1, 0), WW-1);
        int yi0 = min(max(iy0, 0), HH-1), yi1 = min(max(iy1, 0), HH-1);
        int base = ts*DD;
        off[s][0] = base + yi0*WW + xi0; wgt[s][0] = (inx0 && iny0) ? wx0*wy0 : 0.f;
        off[s][1] = base + yi0*WW + xi1; wgt[s][1] = (inx1 && iny0) ? wx1*wy0 : 0.f;
        off[s][2] = base + yi1*WW + xi0; wgt[s][2] = (inx0 && iny1) ? wx0*wy1 : 0.f;
        off[s][3] = base + yi1*WW + xi1; wgt[s][3] = (inx1 && iny1) ? wx1*wy1 : 0.f;
    }
}

// Poses for batch b, threads 0..8 (ts=tid+1): pose = P[ts-1] - P[b],
// P = fp32 sequential cumsum of dp (matches reference rounding).
__device__ __forceinline__ void pose_setup(const float* __restrict__ dp, int b,
                                           float4* __restrict__ pose) {
    if (threadIdx.x < TT-1) {
        int ts = (int)threadIdx.x + 1;
        float ax = 0.f, ay = 0.f, az = 0.f;
        for (int j = 0; j < ts-1; ++j) { ax += dp[3*j]; ay += dp[3*j+1]; az += dp[3*j+2]; }
        float bx = 0.f, by = 0.f, bz = 0.f;
        for (int j = 0; j < b; ++j)    { bx += dp[3*j]; by += dp[3*j+1]; bz += dp[3*j+2]; }
        float yaw = az - bz;
        pose[threadIdx.x] = make_float4(ax - bx, ay - by,
                                        (float)cos((double)yaw), (float)sin((double)yaw));
    }
}

// ---------------- kernel A: fused warp + Gram partials -----------------------
// Block: 64 pixels x 4 waves; wave wv handles channels wv*4 .. wv*4+3.
// Grid: (NCH=66, TT).  partial[b][k][chunk], k = upper-tri pair index.
__global__ __launch_bounds__(256) void gram_fused_kernel(const float* __restrict__ ff,
                                                         const float* __restrict__ dp,
                                                         float* __restrict__ partial) {
    int b = blockIdx.y;
    int lane = threadIdx.x & 63, wv = threadIdx.x >> 6;
    int p = blockIdx.x*64 + lane;
    __shared__ float4 pose[TT-1];
    pose_setup(dp, b, pose);
    __syncthreads();

    int off[TT][4]; float wgt[TT][4];
    slot_setup(b, p, pose, off, wgt);

    float acc[NACC];
    #pragma unroll
    for (int k = 0; k < NACC; ++k) acc[k] = 0.f;

    #pragma unroll
    for (int i = 0; i < 4; ++i) {
        int ch = wv*4 + i;
        const float* fc = ff + ch*HW;
        float v[TT];
        #pragma unroll
        for (int s = 0; s < TT; ++s) {
            if (s + b >= TT-1) {   // wave-uniform validity (incl. s==9)
                v[s] = fc[off[s][0]]*wgt[s][0] + fc[off[s][1]]*wgt[s][1]
                     + fc[off[s][2]]*wgt[s][2] + fc[off[s][3]]*wgt[s][3];
            } else v[s] = 0.f;
        }
        int k = 0;
        #pragma unroll
        for (int t = 0; t < TT; ++t)
            #pragma unroll
            for (int s2 = t; s2 < TT; ++s2)
                acc[k++] += v[t]*v[s2];
    }

    __shared__ float red[NACC*4];
    #pragma unroll
    for (int k = 0; k < NACC; ++k) {
        float a = acc[k];
        #pragma unroll
        for (int o = 32; o > 0; o >>= 1) a += __shfl_down(a, o);
        if (lane == 0) red[k*4 + wv] = a;
    }
    __syncthreads();
    if (threadIdx.x < NACC) {
        float a = red[threadIdx.x*4] + red[threadIdx.x*4+1]
                + red[threadIdx.x*4+2] + red[threadIdx.x*4+3];
        partial[((size_t)b*NACC + threadIdx.x)*NCH + blockIdx.x] = a;
    }
}

// ---------------- kernel B: softmax weights (deterministic) ------------------
// w[b,s] = (1/T) * sum_t softmax(scores[b,t,:])[s]
__global__ __launch_bounds__(256) void weights_kernel(const float* __restrict__ partial,
                                                      float* __restrict__ w) {
    __shared__ float sc[TT*NACC];     // scores per (b, pair-k)
    __shared__ float mx_l[TT*TT], den_l[TT*TT];
    int tid = threadIdx.x;
    // stage A: reduce chunks (contiguous runs of NCH)
    for (int pr = tid; pr < TT*NACC; pr += 256) {
        const float* src = partial + (size_t)pr*NCH;
        float sum = 0.f;
        for (int c = 0; c < NCH; ++c) sum += src[c];
        sc[pr] = sum;
    }
    __syncthreads();
    // stage B: per (b,t) row max + denom
    if (tid < TT*TT) {
        int b = tid / TT, t = tid % TT;
        const float* scb = sc + b*NACC;
        float mx = -1e30f;
        #pragma unroll
        for (int s = 0; s < TT; ++s) {
            int a0 = min(t, s), a1 = max(t, s);
            int k = a0*TT - a0*(a0-1)/2 + (a1 - a0);
            mx = fmaxf(mx, scb[k]);
        }
        float den = 0.f;
        #pragma unroll
        for (int s = 0; s < TT; ++s) {
            int a0 = min(t, s), a1 = max(t, s);
            int k = a0*TT - a0*(a0-1)/2 + (a1 - a0);
            den += expf(scb[k] - mx);
        }
        mx_l[tid] = mx; den_l[tid] = den;
    }
    __syncthreads();
    // stage C: per (b,s) average over t
    if (tid < TT*TT) {
        int b = tid / TT, s = tid % TT;
        const float* scb = sc + b*NACC;
        float acc = 0.f;
        #pragma unroll
        for (int t = 0; t < TT; ++t) {
            int a0 = min(t, s), a1 = max(t, s);
            int k = a0*TT - a0*(a0-1)/2 + (a1 - a0);
            acc += expf(scb[k] - mx_l[b*TT + t]) / den_l[b*TT + t];
        }
        w[tid] = acc * 0.1f;
    }
}

// ---------------- kernel C: fused warp + weighted output ---------------------
// out[b,ch,p] = sum_s w[b,s] * warp_s(ff)[ch,p]   (w folded into wgt)
__global__ __launch_bounds__(256) void out_fused_kernel(const float* __restrict__ ff,
                                                        const float* __restrict__ dp,
                                                        const float* __restrict__ w,
                                                        float* __restrict__ out) {
    int b = blockIdx.y;
    int lane = threadIdx.x & 63, wv = threadIdx.x >> 6;
    int p = blockIdx.x*64 + lane;
    __shared__ float4 pose[TT-1];
    __shared__ float wl[TT];
    pose_setup(dp, b, pose);
    if (threadIdx.x < TT) wl[threadIdx.x] = w[b*TT + threadIdx.x];
    __syncthreads();

    int off[TT][4]; float wgt[TT][4];
    slot_setup(b, p, pose, off, wgt);
    #pragma unroll
    for (int s = 0; s < TT; ++s) {
        float wb = wl[s];
        #pragma unroll
        for (int j = 0; j < 4; ++j) wgt[s][j] *= wb;
    }

    #pragma unroll
    for (int i = 0; i < 4; ++i) {
        int ch = wv*4 + i;
        const float* fc = ff + ch*HW;
        float o = 0.f;
        #pragma unroll
        for (int s = 0; s < TT; ++s) {
            if (s + b >= TT-1) {
                o += fc[off[s][0]]*wgt[s][0] + fc[off[s][1]]*wgt[s][1]
                   + fc[off[s][2]]*wgt[s][2] + fc[off[s][3]]*wgt[s][3];
            }
        }
        out[(size_t)b*DD + ch*HW + p] = o;
    }
}

extern "C" void kernel_launch(void* const* d_in, const int* in_sizes, int n_in,
                              void* d_out, int out_size, void* d_ws, size_t ws_size,
                              hipStream_t stream) {
    const float* ff = (const float*)d_in[0];   // (T, L, C) = (T, D) flat
    const float* dp = (const float*)d_in[1];   // (T, 3)
    float* out = (float*)d_out;                // (T, L, C) flat

    char* ws = (char*)d_ws;
    float* partial = (float*)ws;               // 10*55*66*4 = 145.2 KB
    float* w       = (float*)(ws + 262144);    // 100 floats

    gram_fused_kernel<<<dim3(NCH, TT), 256, 0, stream>>>(ff, dp, partial);
    weights_kernel   <<<1, 256, 0, stream>>>(partial, w);
    out_fused_kernel <<<dim3(NCH, TT), 256, 0, stream>>>(ff, dp, w, out);
}

// Round 4
// 89.846 us; speedup vs baseline: 1.2229x; 1.1320x over previous
//
#include <hip/hip_runtime.h>
#include <math.h>

#define TT 10
#define CHN 16
#define HH 16
#define WW 264
#define HW (HH*WW)          // 4224
#define DD (CHN*HW)         // 67584
#define NCH 66              // pixel chunks of 64 (66*64 == HW exactly)
#define NACC 55             // upper-triangular 10x10 pairs

// Poses for batch b, threads 0..8 (ts=tid+1): pose = P[ts-1] - P[b],
// P = fp32 sequential cumsum of dp (matches reference rounding).
__device__ __forceinline__ void pose_setup(const float* __restrict__ dp, int b,
                                           float4* __restrict__ pose) {
    if (threadIdx.x < TT-1) {
        int ts = (int)threadIdx.x + 1;
        float ax = 0.f, ay = 0.f, az = 0.f;
        for (int j = 0; j < ts-1; ++j) { ax += dp[3*j]; ay += dp[3*j+1]; az += dp[3*j+2]; }
        float bx = 0.f, by = 0.f, bz = 0.f;
        for (int j = 0; j < b; ++j)    { bx += dp[3*j]; by += dp[3*j+1]; bz += dp[3*j+2]; }
        float yaw = az - bz;
        pose[threadIdx.x] = make_float4(ax - bx, ay - by,
                                        (float)cos((double)yaw), (float)sin((double)yaw));
    }
}

// Bilinear plan for ONE slot at pixel (xs,ys): offsets rel. to frame channel 0,
// weights zeroed for OOB corners.  ~25 VALU, ~10 live regs.
__device__ __forceinline__ void plan_slot(float xs, float ys, float4 m,
                                          int& o00, int& o10, int& o01, int& o11,
                                          float& w00, float& w10, float& w01, float& w11) {
    float gx =  m.z*xs + m.w*ys + m.x;
    float gy = -m.w*xs + m.z*ys + m.y;
    float ix = ((gx + 1.f)*(float)WW - 1.f)*0.5f;
    float iy = ((gy + 1.f)*(float)HH - 1.f)*0.5f;
    float ix0f = floorf(ix), iy0f = floorf(iy);
    float wx1 = ix - ix0f, wx0 = 1.f - wx1;
    float wy1 = iy - iy0f, wy0 = 1.f - wy1;
    int ix0 = (int)ix0f, iy0 = (int)iy0f;
    int ix1 = ix0 + 1,   iy1 = iy0 + 1;
    bool inx0 = (ix0 >= 0) && (ix0 < WW);
    bool inx1 = (ix1 >= 0) && (ix1 < WW);
    bool iny0 = (iy0 >= 0) && (iy0 < HH);
    bool iny1 = (iy1 >= 0) && (iy1 < HH);
    int xi0 = min(max(ix0, 0), WW-1), xi1 = min(max(ix1, 0), WW-1);
    int yi0 = min(max(iy0, 0), HH-1), yi1 = min(max(iy1, 0), HH-1);
    float wx0m = inx0 ? wx0 : 0.f, wx1m = inx1 ? wx1 : 0.f;
    float wy0m = iny0 ? wy0 : 0.f, wy1m = iny1 ? wy1 : 0.f;
    o00 = yi0*WW + xi0; o10 = yi0*WW + xi1;
    o01 = yi1*WW + xi0; o11 = yi1*WW + xi1;
    w00 = wx0m*wy0m; w10 = wx1m*wy0m;
    w01 = wx0m*wy1m; w11 = wx1m*wy1m;
}

// ---------------- kernel A: fused warp + Gram partials -----------------------
// Grid (NCH, TT); block = 64 pixels x 4 waves; wave wv owns channels 4wv..4wv+3.
// Per slot: plan (few regs) then one independent 16-load batch -> deep MLP.
__global__ __launch_bounds__(256) void gram_fused_kernel(const float* __restrict__ ff,
                                                         const float* __restrict__ dp,
                                                         float* __restrict__ partial) {
    int b = blockIdx.y;
    int lane = threadIdx.x & 63, wv = threadIdx.x >> 6;
    int p = blockIdx.x*64 + lane;
    __shared__ float4 pose[TT-1];
    pose_setup(dp, b, pose);
    __syncthreads();

    int y = p / WW, x = p - y*WW;
    float xs = (2.f*(float)x + 1.f)*(1.f/(float)WW) - 1.f;
    float ys = (2.f*(float)y + 1.f)*(1.f/(float)HH) - 1.f;

    float v[TT][4];
    #pragma unroll
    for (int s = 0; s < TT; ++s) {
        #pragma unroll
        for (int c = 0; c < 4; ++c) v[s][c] = 0.f;
        if (s == TT-1) {                              // identity slot: direct copy
            const float* src = ff + b*DD + (wv*4)*HW + p;
            #pragma unroll
            for (int c = 0; c < 4; ++c) v[s][c] = src[c*HW];
            continue;
        }
        int ts = (TT-1) - s;
        if (ts > b) continue;                         // invalid -> zeros (uniform)
        int o00,o10,o01,o11; float w00,w10,w01,w11;
        plan_slot(xs, ys, pose[ts-1], o00,o10,o01,o11, w00,w10,w01,w11);
        const float* src = ff + ts*DD + (wv*4)*HW;
        #pragma unroll
        for (int c = 0; c < 4; ++c) {
            const float* fc = src + c*HW;
            v[s][c] = fc[o00]*w00 + fc[o10]*w10 + fc[o01]*w01 + fc[o11]*w11;
        }
    }

    float acc[NACC];
    #pragma unroll
    for (int k = 0; k < NACC; ++k) acc[k] = 0.f;
    #pragma unroll
    for (int c = 0; c < 4; ++c) {
        int k = 0;
        #pragma unroll
        for (int t = 0; t < TT; ++t)
            #pragma unroll
            for (int s2 = t; s2 < TT; ++s2)
                acc[k++] += v[t][c]*v[s2][c];
    }

    __shared__ float red[NACC*4];
    #pragma unroll
    for (int k = 0; k < NACC; ++k) {
        float a = acc[k];
        #pragma unroll
        for (int o = 32; o > 0; o >>= 1) a += __shfl_down(a, o);
        if (lane == 0) red[k*4 + wv] = a;
    }
    __syncthreads();
    if (threadIdx.x < NACC) {
        float a = red[threadIdx.x*4] + red[threadIdx.x*4+1]
                + red[threadIdx.x*4+2] + red[threadIdx.x*4+3];
        partial[((size_t)b*NACC + threadIdx.x)*NCH + blockIdx.x] = a;
    }
}

// ---------------- kernel B: softmax weights (deterministic) ------------------
// w[b,s] = (1/T) * sum_t softmax(scores[b,t,:])[s]
__global__ __launch_bounds__(256) void weights_kernel(const float* __restrict__ partial,
                                                      float* __restrict__ w) {
    __shared__ float sc[TT*NACC];
    __shared__ float mx_l[TT*TT], den_l[TT*TT];
    int tid = threadIdx.x;
    for (int pr = tid; pr < TT*NACC; pr += 256) {
        const float* src = partial + (size_t)pr*NCH;
        float sum = 0.f;
        for (int c = 0; c < NCH; ++c) sum += src[c];
        sc[pr] = sum;
    }
    __syncthreads();
    if (tid < TT*TT) {
        int b = tid / TT, t = tid % TT;
        const float* scb = sc + b*NACC;
        float mx = -1e30f;
        #pragma unroll
        for (int s = 0; s < TT; ++s) {
            int a0 = min(t, s), a1 = max(t, s);
            int k = a0*TT - a0*(a0-1)/2 + (a1 - a0);
            mx = fmaxf(mx, scb[k]);
        }
        float den = 0.f;
        #pragma unroll
        for (int s = 0; s < TT; ++s) {
            int a0 = min(t, s), a1 = max(t, s);
            int k = a0*TT - a0*(a0-1)/2 + (a1 - a0);
            den += expf(scb[k] - mx);
        }
        mx_l[tid] = mx; den_l[tid] = den;
    }
    __syncthreads();
    if (tid < TT*TT) {
        int b = tid / TT, s = tid % TT;
        const float* scb = sc + b*NACC;
        float acc = 0.f;
        #pragma unroll
        for (int t = 0; t < TT; ++t) {
            int a0 = min(t, s), a1 = max(t, s);
            int k = a0*TT - a0*(a0-1)/2 + (a1 - a0);
            acc += expf(scb[k] - mx_l[b*TT + t]) / den_l[b*TT + t];
        }
        w[tid] = acc * 0.1f;
    }
}

// ---------------- kernel C: fused warp + weighted output ---------------------
// out[b,ch,p] = sum_s w[b,s] * warp_s(ff)[ch,p]; per-slot plan, w folded in.
__global__ __launch_bounds__(256) void out_fused_kernel(const float* __restrict__ ff,
                                                        const float* __restrict__ dp,
                                                        const float* __restrict__ w,
                                                        float* __restrict__ out) {
    int b = blockIdx.y;
    int lane = threadIdx.x & 63, wv = threadIdx.x >> 6;
    int p = blockIdx.x*64 + lane;
    __shared__ float4 pose[TT-1];
    __shared__ float wl[TT];
    pose_setup(dp, b, pose);
    if (threadIdx.x < TT) wl[threadIdx.x] = w[b*TT + threadIdx.x];
    __syncthreads();

    int y = p / WW, x = p - y*WW;
    float xs = (2.f*(float)x + 1.f)*(1.f/(float)WW) - 1.f;
    float ys = (2.f*(float)y + 1.f)*(1.f/(float)HH) - 1.f;

    float o[4] = {0.f, 0.f, 0.f, 0.f};
    #pragma unroll
    for (int s = 0; s < TT; ++s) {
        if (s == TT-1) {
            float wb = wl[s];
            const float* src = ff + b*DD + (wv*4)*HW + p;
            #pragma unroll
            for (int c = 0; c < 4; ++c) o[c] += wb*src[c*HW];
            continue;
        }
        int ts = (TT-1) - s;
        if (ts > b) continue;
        int o00,o10,o01,o11; float w00,w10,w01,w11;
        plan_slot(xs, ys, pose[ts-1], o00,o10,o01,o11, w00,w10,w01,w11);
        float wb = wl[s];
        w00 *= wb; w10 *= wb; w01 *= wb; w11 *= wb;
        const float* src = ff + ts*DD + (wv*4)*HW;
        #pragma unroll
        for (int c = 0; c < 4; ++c) {
            const float* fc = src + c*HW;
            o[c] += fc[o00]*w00 + fc[o10]*w10 + fc[o01]*w01 + fc[o11]*w11;
        }
    }
    #pragma unroll
    for (int c = 0; c < 4; ++c)
        out[(size_t)b*DD + (wv*4 + c)*HW + p] = o[c];
}

extern "C" void kernel_launch(void* const* d_in, const int* in_sizes, int n_in,
                              void* d_out, int out_size, void* d_ws, size_t ws_size,
                              hipStream_t stream) {
    const float* ff = (const float*)d_in[0];   // (T, L, C) = (T, D) flat
    const float* dp = (const float*)d_in[1];   // (T, 3)
    float* out = (float*)d_out;                // (T, L, C) flat

    char* ws = (char*)d_ws;
    float* partial = (float*)ws;               // 10*55*66*4 = 145.2 KB
    float* w       = (float*)(ws + 262144);    // 100 floats

    gram_fused_kernel<<<dim3(NCH, TT), 256, 0, stream>>>(ff, dp, partial);
    weights_kernel   <<<1, 256, 0, stream>>>(partial, w);
    out_fused_kernel <<<dim3(NCH, TT), 256, 0, stream>>>(ff, dp, w, out);
}